// Round 11
// baseline (1908.974 us; speedup 1.0000x reference)
//
#include <hip/hip_runtime.h>
#include <stdint.h>

#define NB 8
#define NPTS 4096
#define NPOINT 1024
#define NSAMPLE 32
#define FCH 64
#define HID 128
#define CAPW 160  // per-wave candidate capacity (expected ~15/segment)

typedef unsigned long long ull;

// d2 computed with EXACT numpy rounding/order: ((dx*dx + dy*dy) + dz*dz),
// no FMA contraction (FPS argmax + radius selection must match ref bitwise).
__device__ __forceinline__ float d2_exact(float ax, float ay, float az,
                                          float bx, float by, float bz) {
  float dx = ax - bx, dy = ay - by, dz = az - bz;
  return __fadd_rn(__fadd_rn(__fmul_rn(dx, dx), __fmul_rn(dy, dy)),
                   __fmul_rn(dz, dz));
}

// DPP f32 max step (identity 0 valid: dists >= 0). VALU pipe.
#define DPPMAX(v, ctrl)                                                     \
  v = fmaxf(v, __int_as_float(__builtin_amdgcn_update_dpp(                  \
                 0, __float_as_int(v), ctrl, 0xf, 0xf, true)))

// ---------------- shared memory ---------------------------------------------
// R4..R10 post-mortem: consumer throughput flat ~8 q/us across wave counts,
// tile shapes, A-instruction counts. The invariant was W-stream bytes/query
// (2 MB, L2-resident, L1-uncacheable). This round: 8-sample x 4-channel
// per-thread tile + NQ=2 -> 1 MB W/query. LDS ~84KB -> 1 block/CU
// (producers structurally solo).
struct ProdS {
  float4 pts[NPTS];     // 64 KB
  float chunk[64 * 3];  // 64-centroid publish buffer
  float4 wkd4[2];       // per-wave max dist (parity dbuf)
  int4 wki4[2];         // per-wave argmax idx
};
struct ConsS {
  float fin[64][68];  // 64 samples (2 queries): dxyz 0..2, feats 3..66
  float fm[2][HID];   // per-query mean
  int sidx[64];       // 2 queries x 32 samples
  int scnt[4];
  int tkS;
  union {  // knn candidates overlaid on GEMM buffers (dead during knn)
    float bufA[64][HID];  // h1 then h2 (32 KB)
    ull candseg[4][CAPW];
  };
  union {
    float fp[64][HID];  // f_prime (32 KB)
    ull cand2[4 * CAPW];
  };
};
union SMemU {
  ProdS p;
  ConsS c;
  unsigned char pad_[86016];  // 84 KB > 80 KB -> 1 block/CU guaranteed
};

// ---------------------------------------------------------------- FPS
// R3/R4-proven 256-thread chain (626us solo). Publishes centroids in
// 64-chunks (flush stores + threadfence, barrier, release progress[b]).
__device__ void run_fps(const float* __restrict__ xyz,
                        float* __restrict__ newxyz, int* progress, int b,
                        ProdS& S) {
  const int t = threadIdx.x;
  const int wid = t >> 6;
  const float* src = xyz + (size_t)b * NPTS * 3;
  float* dstb = newxyz + (size_t)b * NPOINT * 3;
  for (int j = t; j < NPTS; j += 256) {
    const float* p = src + 3 * j;
    S.pts[j] = make_float4(p[0], p[1], p[2], 0.f);
  }
  __syncthreads();
  const int base = t * 16;
  float px[16], py[16], pz[16], dist[16];
  const float4 c0 = S.pts[0];
  float bv = -INFINITY;
  int br = 0;
#pragma unroll
  for (int r = 0; r < 16; ++r) {
    float4 p = S.pts[base + r];
    px[r] = p.x; py[r] = p.y; pz[r] = p.z;
    dist[r] = d2_exact(px[r], py[r], pz[r], c0.x, c0.y, c0.z);
    bool c = dist[r] > bv;  // strict > keeps lowest r (idx) on ties
    bv = c ? dist[r] : bv;
    br = c ? r : br;
  }
  if (t == 0) {
    S.chunk[0] = c0.x; S.chunk[1] = c0.y; S.chunk[2] = c0.z;
  }
  for (int it = 1; it < NPOINT; ++it) {
    float wm = bv;
    DPPMAX(wm, 0x111); DPPMAX(wm, 0x112); DPPMAX(wm, 0x114); DPPMAX(wm, 0x118);
    DPPMAX(wm, 0x142); DPPMAX(wm, 0x143);
    float gmaxw =
        __int_as_float(__builtin_amdgcn_readlane(__float_as_int(wm), 63));
    ull m = __ballot(bv == gmaxw);
    int lead = __ffsll((long long)m) - 1;  // lowest lane == lowest index
    int widx = __builtin_amdgcn_readlane(base + br, lead);
    const int par = it & 1;
    if ((t & 63) == 0) {
      ((float*)&S.wkd4[par])[wid] = gmaxw;
      ((int*)&S.wki4[par])[wid] = widx;
    }
    __syncthreads();  // parity double-buffer -> single barrier/iter
    if ((it & 63) == 0) {
      if (t < 192) {
        dstb[(it - 64) * 3 + t] = S.chunk[t];
        __threadfence();
      }
      __syncthreads();
      if (t == 0)
        __hip_atomic_store(&progress[b], it, __ATOMIC_RELEASE,
                           __HIP_MEMORY_SCOPE_AGENT);
    }
    float4 dd = S.wkd4[par];
    int4 ii = S.wki4[par];
    float d = dd.x; int fi = ii.x;
    bool c1 = (dd.y > d) || (dd.y == d && ii.y < fi);
    d = c1 ? dd.y : d; fi = c1 ? ii.y : fi;
    bool c2 = (dd.z > d) || (dd.z == d && ii.z < fi);
    d = c2 ? dd.z : d; fi = c2 ? ii.z : fi;
    bool c3 = (dd.w > d) || (dd.w == d && ii.w < fi);
    fi = c3 ? ii.w : fi;
    const float4 cp = S.pts[fi];
    if (t == 0) {
      int slot = (it & 63) * 3;
      S.chunk[slot + 0] = cp.x;
      S.chunk[slot + 1] = cp.y;
      S.chunk[slot + 2] = cp.z;
    }
    bv = -INFINITY;
    br = 0;
#pragma unroll
    for (int r = 0; r < 16; ++r) {
      float dnew = d2_exact(px[r], py[r], pz[r], cp.x, cp.y, cp.z);
      float nd = fminf(dist[r], dnew);
      dist[r] = nd;
      bool c = nd > bv;
      bv = c ? nd : bv;
      br = c ? r : br;
    }
  }
  __syncthreads();  // chunk holds centroids [960,1024)
  if (t < 192) {
    dstb[(NPOINT - 64) * 3 + t] = S.chunk[t];
    __threadfence();
  }
  __syncthreads();
  if (t == 0)
    __hip_atomic_store(&progress[b], NPOINT, __ATOMIC_RELEASE,
                       __HIP_MEMORY_SCOPE_AGENT);
}

// ---------------------------------------------------------------- MLP gemms
// 8-sample x 4-channel per-thread tile. Each W float4 feeds 8 samples
// (vs R4's 4) -> W-stream bytes per query halve. Plain loops (R7 lesson).
template <int K, int LDA>
__device__ __forceinline__ void gemm8(const float* __restrict__ Ab,
                                      const float* __restrict__ W,
                                      float acc[8][4]) {
  int k = 0;
  for (; k + 4 <= K; k += 4) {
    float4 Ar[8];
#pragma unroll
    for (int i = 0; i < 8; ++i)
      Ar[i] = *(const float4*)(Ab + (size_t)i * LDA + k);
#pragma unroll
    for (int kk = 0; kk < 4; ++kk) {
      float4 w = *(const float4*)(W + (size_t)(k + kk) * HID);
#pragma unroll
      for (int i = 0; i < 8; ++i) {
        float e = (&Ar[i].x)[kk];
        acc[i][0] += e * w.x; acc[i][1] += e * w.y;
        acc[i][2] += e * w.z; acc[i][3] += e * w.w;
      }
    }
  }
  for (; k < K; ++k) {
    float4 w = *(const float4*)(W + (size_t)k * HID);
#pragma unroll
    for (int i = 0; i < 8; ++i) {
      float e = Ab[(size_t)i * LDA + k];
      acc[i][0] += e * w.x; acc[i][1] += e * w.y;
      acc[i][2] += e * w.z; acc[i][3] += e * w.w;
    }
  }
}

// K=128 variant also accumulating corr[j] = sum_k fm[k]*W[k][j]
__device__ __forceinline__ void gemm8_corr(const float* __restrict__ Ab,
                                           const float* __restrict__ W,
                                           const float* __restrict__ fm,
                                           float acc[8][4], float corr[4]) {
  for (int k = 0; k < HID; k += 4) {
    float4 Ar[8];
#pragma unroll
    for (int i = 0; i < 8; ++i)
      Ar[i] = *(const float4*)(Ab + (size_t)i * HID + k);
    float4 FM = *(const float4*)(fm + k);
#pragma unroll
    for (int kk = 0; kk < 4; ++kk) {
      float4 w = *(const float4*)(W + (size_t)(k + kk) * HID);
      float cf = (&FM.x)[kk];
      corr[0] += cf * w.x; corr[1] += cf * w.y;
      corr[2] += cf * w.z; corr[3] += cf * w.w;
#pragma unroll
      for (int i = 0; i < 8; ++i) {
        float e = (&Ar[i].x)[kk];
        acc[i][0] += e * w.x; acc[i][1] += e * w.y;
        acc[i][2] += e * w.z; acc[i][3] += e * w.w;
      }
    }
  }
}

// ---------------------------------------------------------------- consumer
// 256 threads, 2 queries per pass. sg = t>>5 (8 groups x 8 samples = 64
// samples); groups 0-3 -> query 0, 4-7 -> query 1. c0 = (t&31)*4.
__device__ void run_consumer(const float* __restrict__ xyz,
                             const float* __restrict__ feats,
                             const float* __restrict__ W1f,
                             const float* __restrict__ b1f,
                             const float* __restrict__ W2f,
                             const float* __restrict__ b2f,
                             const float* __restrict__ W1w,
                             const float* __restrict__ b1w,
                             const float* __restrict__ W2w,
                             const float* __restrict__ b2w,
                             const float* __restrict__ newxyz,
                             float* __restrict__ fout, int* progress,
                             int* ticket, ConsS& S) {
  const int t = threadIdx.x;
  const int wv = t >> 6;
  const int lane = t & 63;
  const float r2 = 0.0225f;  // np float32(RADIUS**2)

  while (true) {
    if (t == 0) S.tkS = atomicAdd(ticket, 1);
    __syncthreads();
    const int tk = S.tkS;
    if (tk >= NB * NPOINT / 2) return;
    const int i2 = tk >> 3;  // query-pair index
    const int b = tk & 7;
    const int it0 = 2 * i2;  // queries it0, it0+1 of batch b
    const int g0 = b * NPOINT + it0;

    // wait until centroid it0+1 of batch b is published (R8-proven scheme)
    if (t == 0) {
      while (__hip_atomic_load(&progress[b], __ATOMIC_RELAXED,
                               __HIP_MEMORY_SCOPE_AGENT) <= it0 + 1)
        __builtin_amdgcn_s_sleep(32);
    }
    __syncthreads();
    {
      int pv = __hip_atomic_load(&progress[b], __ATOMIC_ACQUIRE,
                                 __HIP_MEMORY_SCOPE_AGENT);
      while (pv <= it0 + 1) {
        __builtin_amdgcn_s_sleep(8);
        pv = __hip_atomic_load(&progress[b], __ATOMIC_ACQUIRE,
                               __HIP_MEMORY_SCOPE_AGENT);
      }
    }
    const float* src = xyz + (size_t)b * NPTS * 3;

    // ---- knn x2 (sequential): 4-wave scan, compaction, rank-select 32
    for (int qq = 0; qq < 2; ++qq) {
      const int g = g0 + qq;
      const float cx = newxyz[g * 3 + 0];
      const float cy = newxyz[g * 3 + 1];
      const float cz = newxyz[g * 3 + 2];
      int cnt = 0;
      const int jb = wv * 1024;
      for (int j0 = jb; j0 < jb + 1024; j0 += 64) {
        const int p = j0 + lane;
        const float* pp = src + p * 3;
        float d2 = d2_exact(pp[0], pp[1], pp[2], cx, cy, cz);
        bool inr = (d2 <= r2);
        ull mask = __ballot(inr);
        if (inr) {
          int pos = cnt + __popcll(mask & ((1ull << lane) - 1ull));
          if (pos < CAPW)
            S.candseg[wv][pos] =
                ((ull)__float_as_uint(d2) << 32) | (unsigned)p;
        }
        cnt += __popcll(mask);
      }
      if (lane == 0) S.scnt[wv] = cnt < CAPW ? cnt : CAPW;
      __syncthreads();
      const int n0 = S.scnt[0], n1 = S.scnt[1], n2 = S.scnt[2], n3 = S.scnt[3];
      const int C = n0 + n1 + n2 + n3;
      {
        int off = (wv > 0 ? n0 : 0) + (wv > 1 ? n1 : 0) + (wv > 2 ? n2 : 0);
        int myn = S.scnt[wv];
        for (int i = lane; i < myn; i += 64)
          S.cand2[off + i] = S.candseg[wv][i];
      }
      __syncthreads();
      for (int tt = t; tt < C; tt += 256) {
        ull key = S.cand2[tt];
        int rank = 0;
        for (int u = 0; u < C; ++u) rank += (S.cand2[u] < key) ? 1 : 0;
        if (rank < NSAMPLE)
          S.sidx[qq * NSAMPLE + rank] = (int)(key & 0xffffffffu);
      }
      if (C < NSAMPLE && wv == 0) {  // boundary fill: lowest-idx outside pts
        const float* pp = src + lane * 3;
        float d2 = d2_exact(pp[0], pp[1], pp[2], cx, cy, cz);
        bool outr = !(d2 <= r2);
        ull mask = __ballot(outr);
        if (outr) {
          int pos = __popcll(mask & ((1ull << lane) - 1ull));
          if (pos < NSAMPLE - C) S.sidx[qq * NSAMPLE + C + pos] = lane;
        }
      }
      __syncthreads();
    }

    // ---- stage f_in for 64 samples (2 queries)
    if (t < 64) {
      const int g = g0 + (t >> 5);
      const float cx = newxyz[g * 3 + 0];
      const float cy = newxyz[g * 3 + 1];
      const float cz = newxyz[g * 3 + 2];
      const float* pp = src + (size_t)S.sidx[t] * 3;
      S.fin[t][0] = pp[0] - cx;
      S.fin[t][1] = pp[1] - cy;
      S.fin[t][2] = pp[2] - cz;
      S.fin[t][67] = 0.f;
    }
    for (int e = t; e < 64 * FCH; e += 256) {
      int s = e >> 6;
      int c = e & 63;
      S.fin[s][3 + c] = feats[((size_t)b * NPTS + S.sidx[s]) * FCH + c];
    }
    __syncthreads();

    const int sg = t >> 5;       // 0..7
    const int s0 = sg * 8;       // 8 samples per thread
    const int c0 = (t & 31) * 4; // 4 channels per thread
    const int q = sg >> 2;       // this thread's query (0/1)
    float acc[8][4];

    // G1: relu(f_in @ W1f + b1f) -> bufA
    {
      float4 bv4 = *(const float4*)(b1f + c0);
#pragma unroll
      for (int i = 0; i < 8; ++i) {
        acc[i][0] = bv4.x; acc[i][1] = bv4.y;
        acc[i][2] = bv4.z; acc[i][3] = bv4.w;
      }
    }
    gemm8<67, 68>(&S.fin[s0][0], W1f + c0, acc);
#pragma unroll
    for (int i = 0; i < 8; ++i)
#pragma unroll
      for (int j = 0; j < 4; ++j)
        S.bufA[s0 + i][c0 + j] = fmaxf(acc[i][j], 0.f);
    __syncthreads();

    // G2: relu(h1 @ W2f + b2f) -> fp
    {
      float4 bv4 = *(const float4*)(b2f + c0);
#pragma unroll
      for (int i = 0; i < 8; ++i) {
        acc[i][0] = bv4.x; acc[i][1] = bv4.y;
        acc[i][2] = bv4.z; acc[i][3] = bv4.w;
      }
    }
    gemm8<128, HID>(&S.bufA[s0][0], W2f + c0, acc);
#pragma unroll
    for (int i = 0; i < 8; ++i)
#pragma unroll
      for (int j = 0; j < 4; ++j)
        S.fp[s0 + i][c0 + j] = fmaxf(acc[i][j], 0.f);
    __syncthreads();

    // per-query mean over 32 samples
    {
      int qm = t >> 7;  // 0/1
      int ch = t & 127;
      float s = 0.f;
#pragma unroll 8
      for (int i = 0; i < 32; ++i) s += S.fp[qm * 32 + i][ch];
      S.fm[qm][ch] = s * (1.0f / 32.0f);
    }
    __syncthreads();

    // G3: relu( fp@W1w[3:] + (b1w + dxyz@W1w[0:3]) - fm@W1w[3:] ) -> bufA
    float corr[4] = {0.f, 0.f, 0.f, 0.f};
    {
      float4 bv4 = *(const float4*)(b1w + c0);
      float4 w0 = *(const float4*)(W1w + 0 * HID + c0);
      float4 w1 = *(const float4*)(W1w + 1 * HID + c0);
      float4 w2 = *(const float4*)(W1w + 2 * HID + c0);
#pragma unroll
      for (int i = 0; i < 8; ++i) {
        float dx = S.fin[s0 + i][0], dy = S.fin[s0 + i][1],
              dz = S.fin[s0 + i][2];
        acc[i][0] = bv4.x + dx * w0.x + dy * w1.x + dz * w2.x;
        acc[i][1] = bv4.y + dx * w0.y + dy * w1.y + dz * w2.y;
        acc[i][2] = bv4.z + dx * w0.z + dy * w1.z + dz * w2.z;
        acc[i][3] = bv4.w + dx * w0.w + dy * w1.w + dz * w2.w;
      }
    }
    gemm8_corr(&S.fp[s0][0], W1w + 3 * HID + c0, S.fm[q], acc, corr);
    __syncthreads();  // h1 reads done before bufA overwrite with h2
#pragma unroll
    for (int i = 0; i < 8; ++i)
#pragma unroll
      for (int j = 0; j < 4; ++j)
        S.bufA[s0 + i][c0 + j] = fmaxf(acc[i][j] - corr[j], 0.f);
    __syncthreads();

    // G4: alpha = sigmoid(h2 @ W2w + b2w); f_out = sum_s alpha*f'
    {
      float4 bv4 = *(const float4*)(b2w + c0);
#pragma unroll
      for (int i = 0; i < 8; ++i) {
        acc[i][0] = bv4.x; acc[i][1] = bv4.y;
        acc[i][2] = bv4.z; acc[i][3] = bv4.w;
      }
    }
    gemm8<128, HID>(&S.bufA[s0][0], W2w + c0, acc);
    {
      float part[4] = {0.f, 0.f, 0.f, 0.f};
#pragma unroll
      for (int i = 0; i < 8; ++i)
#pragma unroll
        for (int j = 0; j < 4; ++j) {
          float al = 1.0f / (1.0f + __expf(-acc[i][j]));
          part[j] += al * S.fp[s0 + i][c0 + j];
        }
      __syncthreads();  // fin dead -> reuse as red[8][HID]
      float* redp = &S.fin[0][0];
      redp[sg * HID + c0 + 0] = part[0];
      redp[sg * HID + c0 + 1] = part[1];
      redp[sg * HID + c0 + 2] = part[2];
      redp[sg * HID + c0 + 3] = part[3];
    }
    __syncthreads();
    {
      int qm = t >> 7;  // 0/1
      int ch = t & 127;
      float* redp = &S.fin[0][0];
      float s = 0.f;
#pragma unroll
      for (int w = 0; w < 4; ++w) s += redp[(qm * 4 + w) * HID + ch];
      fout[(size_t)(g0 + qm) * HID + ch] = s;
    }
    __syncthreads();  // LDS fully consumed before next ticket
  }
}

// ---------------------------------------------------------------- fused
__global__ __launch_bounds__(256, 1) void sa_fused_kernel(
    const float* __restrict__ xyz, const float* __restrict__ feats,
    const float* __restrict__ W1f, const float* __restrict__ b1f,
    const float* __restrict__ W2f, const float* __restrict__ b2f,
    const float* __restrict__ W1w, const float* __restrict__ b1w,
    const float* __restrict__ W2w, const float* __restrict__ b2w,
    float* __restrict__ newxyz, float* __restrict__ fout, int* ctrl) {
  __shared__ SMemU sm;
  int* progress = ctrl;    // [0..7]
  int* ticket = ctrl + 8;  // [8]
  if (blockIdx.x < NB) {
    run_fps(xyz, newxyz, progress, blockIdx.x, sm.p);
    __syncthreads();  // producer joins consumer pool for the tail
  }
  run_consumer(xyz, feats, W1f, b1f, W2f, b2f, W1w, b1w, W2w, b2w, newxyz,
               fout, progress, ticket, sm.c);
}

extern "C" void kernel_launch(void* const* d_in, const int* in_sizes, int n_in,
                              void* d_out, int out_size, void* d_ws, size_t ws_size,
                              hipStream_t stream) {
  const float* xyz = (const float*)d_in[0];
  const float* feats = (const float*)d_in[1];
  const float* W1f = (const float*)d_in[2];
  const float* b1f = (const float*)d_in[3];
  const float* W2f = (const float*)d_in[4];
  const float* b2f = (const float*)d_in[5];
  const float* W1w = (const float*)d_in[6];
  const float* b1w = (const float*)d_in[7];
  const float* W2w = (const float*)d_in[8];
  const float* b2w = (const float*)d_in[9];

  float* newxyz = (float*)d_out;                          // (8,1024,3)
  float* fout = (float*)d_out + (size_t)NB * NPOINT * 3;  // (8,1024,128)
  int* ctrl = (int*)d_ws;  // progress[8] + ticket[1]

  hipMemsetAsync(ctrl, 0, 64, stream);
  // 256 blocks x 256 thr, 84KB LDS -> 1 block/CU (producers solo). Consumer:
  // NQ=2 + 8-sample x 4-channel tile halves the L2 W-stream per query — the
  // invariant that pinned R4/R8/R9/R10 at ~8 q/us.
  sa_fused_kernel<<<256, 256, 0, stream>>>(xyz, feats, W1f, b1f, W2f, b2f,
                                           W1w, b1w, W2w, b2w, newxyz, fout,
                                           ctrl);
}

// Round 12
// 881.690 us; speedup vs baseline: 2.1651x; 2.1651x over previous
//
#include <hip/hip_runtime.h>
#include <hip/hip_bf16.h>
#include <stdint.h>

#define NB 8
#define NPTS 4096
#define NPOINT 1024
#define NSAMPLE 32
#define FCH 64
#define HID 128
#define CAPW 160  // per-wave candidate capacity (expected ~15/segment)

typedef unsigned long long ull;
typedef __attribute__((ext_vector_type(8))) short short8;
typedef __attribute__((ext_vector_type(4))) float f32x4;

// d2 computed with EXACT numpy rounding/order: ((dx*dx + dy*dy) + dz*dz),
// no FMA contraction (FPS argmax + radius selection must match ref bitwise).
__device__ __forceinline__ float d2_exact(float ax, float ay, float az,
                                          float bx, float by, float bz) {
  float dx = ax - bx, dy = ay - by, dz = az - bz;
  return __fadd_rn(__fadd_rn(__fmul_rn(dx, dx), __fmul_rn(dy, dy)),
                   __fmul_rn(dz, dz));
}

__device__ __forceinline__ unsigned short f2bf(float x) {
  __hip_bfloat16 b = __float2bfloat16(x);
  unsigned short u;
  __builtin_memcpy(&u, &b, 2);
  return u;
}

// DPP f32 max step (identity 0 valid: dists >= 0). VALU pipe.
#define DPPMAX(v, ctrl)                                                     \
  v = fmaxf(v, __int_as_float(__builtin_amdgcn_update_dpp(                  \
                 0, __float_as_int(v), ctrl, 0xf, 0xf, true)))

// ---------------- shared memory ---------------------------------------------
// 84KB pad -> structurally 1 block/CU (R10-proven): producers solo, no
// dispatch-mapping assumptions. Consumer is now MFMA-based: the f32 FMA
// stream (R4-R11: bound by exposed load latency in a barrier-lockstepped
// loop, insensitive to waves/tiles/W-traffic) shrinks ~10x in instructions.
struct ProdS {
  float4 pts[NPTS];     // 64 KB
  float chunk[64 * 3];  // 64-centroid publish buffer
  float4 wkd4[2];       // per-wave max dist (parity dbuf)
  int4 wki4[2];         // per-wave argmax idx
};
struct ConsS {
  alignas(16) unsigned short a1[32][104];   // G1 A: [dxyz,feats,0-pad..95] bf16
  alignas(16) unsigned short hbf[32][136];  // bf16 A for G2 (h1), G3 (fp-fm), G4 (h2)
  float fp32[32][HID];  // f32 f_prime (16KB)
  float fm[HID];
  float dxyz[32][4];
  int sidx[NSAMPLE];
  int scnt[4];
  int tkS;
  ull candseg[4][CAPW];
  ull cand2[4 * CAPW];
};
union SMemU {
  ProdS p;
  ConsS c;
  unsigned char pad_[86016];  // 84KB > 80KB -> 1 block/CU guaranteed
};

// ------------------------------------------------------- weight pre-convert
// d_ws layout (shorts, after 256B ctrl area):
//   WT1f [128][96]  : WT1f[n][k] = k<67 ? W1f[k][n] : 0
//   WT2f [128][128] : = W2f[k][n]
//   WT1w [128][128] : = W1w[3+k][n]   (rows 0..2 handled in G3 epilogue)
//   WT2w [128][128] : = W2w[k][n]
__global__ __launch_bounds__(256) void convert_w(const float* __restrict__ W1f,
                                                 const float* __restrict__ W2f,
                                                 const float* __restrict__ W1w,
                                                 const float* __restrict__ W2w,
                                                 unsigned short* __restrict__ wt) {
  int i = blockIdx.x * 256 + threadIdx.x;
  if (i >= 61440) return;
  float v;
  if (i < 12288) {
    int n = i / 96, k = i - n * 96;
    v = (k < 67) ? W1f[k * HID + n] : 0.f;
  } else if (i < 28672) {
    int j = i - 12288;
    int n = j >> 7, k = j & 127;
    v = W2f[k * HID + n];
  } else if (i < 45056) {
    int j = i - 28672;
    int n = j >> 7, k = j & 127;
    v = W1w[(k + 3) * HID + n];
  } else {
    int j = i - 45056;
    int n = j >> 7, k = j & 127;
    v = W2w[k * HID + n];
  }
  wt[i] = f2bf(v);
}

// ---------------------------------------------------------------- FPS
// R3/R4-proven chain (626us solo). Publishes centroids in 64-chunks.
__device__ void run_fps(const float* __restrict__ xyz,
                        float* __restrict__ newxyz, int* progress, int b,
                        ProdS& S) {
  const int t = threadIdx.x;
  const int wid = t >> 6;
  const float* src = xyz + (size_t)b * NPTS * 3;
  float* dstb = newxyz + (size_t)b * NPOINT * 3;
  for (int j = t; j < NPTS; j += 256) {
    const float* p = src + 3 * j;
    S.pts[j] = make_float4(p[0], p[1], p[2], 0.f);
  }
  __syncthreads();
  const int base = t * 16;
  float px[16], py[16], pz[16], dist[16];
  const float4 c0 = S.pts[0];
  float bv = -INFINITY;
  int br = 0;
#pragma unroll
  for (int r = 0; r < 16; ++r) {
    float4 p = S.pts[base + r];
    px[r] = p.x; py[r] = p.y; pz[r] = p.z;
    dist[r] = d2_exact(px[r], py[r], pz[r], c0.x, c0.y, c0.z);
    bool c = dist[r] > bv;  // strict > keeps lowest r (idx) on ties
    bv = c ? dist[r] : bv;
    br = c ? r : br;
  }
  if (t == 0) {
    S.chunk[0] = c0.x; S.chunk[1] = c0.y; S.chunk[2] = c0.z;
  }
  for (int it = 1; it < NPOINT; ++it) {
    float wm = bv;
    DPPMAX(wm, 0x111); DPPMAX(wm, 0x112); DPPMAX(wm, 0x114); DPPMAX(wm, 0x118);
    DPPMAX(wm, 0x142); DPPMAX(wm, 0x143);
    float gmaxw =
        __int_as_float(__builtin_amdgcn_readlane(__float_as_int(wm), 63));
    ull m = __ballot(bv == gmaxw);
    int lead = __ffsll((long long)m) - 1;  // lowest lane == lowest index
    int widx = __builtin_amdgcn_readlane(base + br, lead);
    const int par = it & 1;
    if ((t & 63) == 0) {
      ((float*)&S.wkd4[par])[wid] = gmaxw;
      ((int*)&S.wki4[par])[wid] = widx;
    }
    __syncthreads();  // parity double-buffer -> single barrier/iter
    if ((it & 63) == 0) {
      if (t < 192) {
        dstb[(it - 64) * 3 + t] = S.chunk[t];
        __threadfence();
      }
      __syncthreads();
      if (t == 0)
        __hip_atomic_store(&progress[b], it, __ATOMIC_RELEASE,
                           __HIP_MEMORY_SCOPE_AGENT);
    }
    float4 dd = S.wkd4[par];
    int4 ii = S.wki4[par];
    float d = dd.x; int fi = ii.x;
    bool c1 = (dd.y > d) || (dd.y == d && ii.y < fi);
    d = c1 ? dd.y : d; fi = c1 ? ii.y : fi;
    bool c2 = (dd.z > d) || (dd.z == d && ii.z < fi);
    d = c2 ? dd.z : d; fi = c2 ? ii.z : fi;
    bool c3 = (dd.w > d) || (dd.w == d && ii.w < fi);
    fi = c3 ? ii.w : fi;
    const float4 cp = S.pts[fi];
    if (t == 0) {
      int slot = (it & 63) * 3;
      S.chunk[slot + 0] = cp.x;
      S.chunk[slot + 1] = cp.y;
      S.chunk[slot + 2] = cp.z;
    }
    bv = -INFINITY;
    br = 0;
#pragma unroll
    for (int r = 0; r < 16; ++r) {
      float dnew = d2_exact(px[r], py[r], pz[r], cp.x, cp.y, cp.z);
      float nd = fminf(dist[r], dnew);
      dist[r] = nd;
      bool c = nd > bv;
      bv = c ? nd : bv;
      br = c ? r : br;
    }
  }
  __syncthreads();  // chunk holds centroids [960,1024)
  if (t < 192) {
    dstb[(NPOINT - 64) * 3 + t] = S.chunk[t];
    __threadfence();
  }
  __syncthreads();
  if (t == 0)
    __hip_atomic_store(&progress[b], NPOINT, __ATOMIC_RELEASE,
                       __HIP_MEMORY_SCOPE_AGENT);
}

// ----------------------------------------------------------- MFMA tile pass
// Wave wv computes 4 tiles of the 2x8 (M=32,N=128) tile grid:
// tile i: mtile=i&1, ntile=wv*2+(i>>1). HW-verified layouts:
// A/B-frag: idx=lane&15 (m for A / n for W^T), k=(lane>>4)*8+j [m120];
// C/D: col=lane&15, row=(lane>>4)*4+reg [m89/m91].
__device__ __forceinline__ void mfma_tiles(const unsigned short* __restrict__ A,
                                           int lda,
                                           const unsigned short* __restrict__ WT,
                                           int ldw, int ksteps, int wv,
                                           int lane, f32x4 acc[4]) {
  const int mi = lane & 15;
  const int qo = (lane >> 4) * 8;
#pragma unroll
  for (int i = 0; i < 4; ++i) {
    const int m = (i & 1) * 16 + mi;
    const int n = (wv * 2 + (i >> 1)) * 16 + mi;
    f32x4 a = {0.f, 0.f, 0.f, 0.f};
    for (int ks = 0; ks < ksteps; ++ks) {
      short8 af = *(const short8*)(A + (size_t)m * lda + ks * 32 + qo);
      short8 bf = *(const short8*)(WT + (size_t)n * ldw + ks * 32 + qo);
      a = __builtin_amdgcn_mfma_f32_16x16x32_bf16(af, bf, a, 0, 0, 0);
    }
    acc[i] = a;
  }
}

// ---------------------------------------------------------------- consumer
__device__ void run_consumer(const float* __restrict__ xyz,
                             const float* __restrict__ feats,
                             const unsigned short* __restrict__ wt,
                             const float* __restrict__ b1f,
                             const float* __restrict__ b2f,
                             const float* __restrict__ W1w,
                             const float* __restrict__ b1w,
                             const float* __restrict__ b2w,
                             const float* __restrict__ newxyz,
                             float* __restrict__ fout, int* progress,
                             int* ticket, ConsS& S) {
  const int t = threadIdx.x;
  const int wv = t >> 6;
  const int lane = t & 63;
  const float r2 = 0.0225f;  // np float32(RADIUS**2)
  const unsigned short* WT1f = wt;
  const unsigned short* WT2f = wt + 12288;
  const unsigned short* WT1w = wt + 28672;
  const unsigned short* WT2w = wt + 45056;

  // zero a1 once (cols 67..103 stay zero across all queries)
  for (int e = t; e < 32 * 104 / 2; e += 256) ((unsigned int*)S.a1)[e] = 0u;
  __syncthreads();

  while (true) {
    if (t == 0) S.tkS = atomicAdd(ticket, 1);
    __syncthreads();
    const int tk = S.tkS;
    if (tk >= NB * NPOINT) return;
    const int it = tk >> 3;
    const int b = tk & 7;
    const int g = b * NPOINT + it;

    // wait until centroid `it` of batch b is published
    if (t == 0) {
      while (__hip_atomic_load(&progress[b], __ATOMIC_RELAXED,
                               __HIP_MEMORY_SCOPE_AGENT) <= it)
        __builtin_amdgcn_s_sleep(32);
    }
    __syncthreads();
    {
      int pv = __hip_atomic_load(&progress[b], __ATOMIC_ACQUIRE,
                                 __HIP_MEMORY_SCOPE_AGENT);
      while (pv <= it) {
        __builtin_amdgcn_s_sleep(8);
        pv = __hip_atomic_load(&progress[b], __ATOMIC_ACQUIRE,
                               __HIP_MEMORY_SCOPE_AGENT);
      }
    }
    const float cx = newxyz[g * 3 + 0];
    const float cy = newxyz[g * 3 + 1];
    const float cz = newxyz[g * 3 + 2];

    // ---- knn (exact f32, R4-proven): scan, compaction, rank-select 32
    const float* src = xyz + (size_t)b * NPTS * 3;
    int cnt = 0;
    const int jb = wv * 1024;
    for (int j0 = jb; j0 < jb + 1024; j0 += 64) {
      const int p = j0 + lane;
      const float* pp = src + p * 3;
      float d2 = d2_exact(pp[0], pp[1], pp[2], cx, cy, cz);
      bool inr = (d2 <= r2);
      ull mask = __ballot(inr);
      if (inr) {
        int pos = cnt + __popcll(mask & ((1ull << lane) - 1ull));
        if (pos < CAPW)
          S.candseg[wv][pos] = ((ull)__float_as_uint(d2) << 32) | (unsigned)p;
      }
      cnt += __popcll(mask);
    }
    if (lane == 0) S.scnt[wv] = cnt < CAPW ? cnt : CAPW;
    __syncthreads();
    const int n0 = S.scnt[0], n1 = S.scnt[1], n2 = S.scnt[2], n3 = S.scnt[3];
    const int C = n0 + n1 + n2 + n3;
    {
      int off = (wv > 0 ? n0 : 0) + (wv > 1 ? n1 : 0) + (wv > 2 ? n2 : 0);
      int myn = S.scnt[wv];
      for (int i = lane; i < myn; i += 64) S.cand2[off + i] = S.candseg[wv][i];
    }
    __syncthreads();
    for (int tt = t; tt < C; tt += 256) {
      ull key = S.cand2[tt];
      int rank = 0;
      for (int u = 0; u < C; ++u) rank += (S.cand2[u] < key) ? 1 : 0;
      if (rank < NSAMPLE) S.sidx[rank] = (int)(key & 0xffffffffu);
    }
    if (C < NSAMPLE && wv == 0) {  // boundary fill: lowest-index outside pts
      const float* pp = src + lane * 3;
      float d2 = d2_exact(pp[0], pp[1], pp[2], cx, cy, cz);
      bool outr = !(d2 <= r2);
      ull mask = __ballot(outr);
      if (outr) {
        int pos = __popcll(mask & ((1ull << lane) - 1ull));
        if (pos < NSAMPLE - C) S.sidx[C + pos] = lane;
      }
    }
    __syncthreads();

    // ---- stage A for G1 (bf16) + dxyz (f32)
    if (t < 32) {
      const float* pp = src + (size_t)S.sidx[t] * 3;
      float dx = pp[0] - cx, dy = pp[1] - cy, dz = pp[2] - cz;
      S.dxyz[t][0] = dx; S.dxyz[t][1] = dy; S.dxyz[t][2] = dz;
      S.dxyz[t][3] = 0.f;
      S.a1[t][0] = f2bf(dx); S.a1[t][1] = f2bf(dy); S.a1[t][2] = f2bf(dz);
    }
    for (int e = t; e < 32 * FCH; e += 256) {
      int s = e >> 6;
      int c = e & 63;
      S.a1[s][3 + c] = f2bf(feats[((size_t)b * NPTS + S.sidx[s]) * FCH + c]);
    }
    __syncthreads();

    f32x4 acc[4];
    const int coli = lane & 15;
    const int rq = (lane >> 4) << 2;  // row offset from quad

    // G1: h1 = relu(f_in @ W1f + b1f), K=96 (zero-padded) -> hbf
    mfma_tiles(&S.a1[0][0], 104, WT1f, 96, 3, wv, lane, acc);
#pragma unroll
    for (int i = 0; i < 4; ++i) {
      int col = (wv * 2 + (i >> 1)) * 16 + coli;
      float bb = b1f[col];
      int rowb = (i & 1) * 16 + rq;
#pragma unroll
      for (int r = 0; r < 4; ++r)
        S.hbf[rowb + r][col] = f2bf(fmaxf(acc[i][r] + bb, 0.f));
    }
    __syncthreads();

    // G2: fp = relu(h1 @ W2f + b2f) -> fp32
    mfma_tiles(&S.hbf[0][0], 136, WT2f, 128, 4, wv, lane, acc);
#pragma unroll
    for (int i = 0; i < 4; ++i) {
      int col = (wv * 2 + (i >> 1)) * 16 + coli;
      float bb = b2f[col];
      int rowb = (i & 1) * 16 + rq;
#pragma unroll
      for (int r = 0; r < 4; ++r)
        S.fp32[rowb + r][col] = fmaxf(acc[i][r] + bb, 0.f);
    }
    __syncthreads();

    // mean over samples
    if (t < HID) {
      float s = 0.f;
#pragma unroll 8
      for (int i = 0; i < 32; ++i) s += S.fp32[i][t];
      S.fm[t] = s * (1.0f / 32.0f);
    }
    __syncthreads();

    // G3 input: bf16(fp - fm) -> hbf (h1 dead)
    for (int e = t; e < 32 * HID; e += 256) {
      int s = e >> 7;
      int c = e & 127;
      S.hbf[s][c] = f2bf(S.fp32[s][c] - S.fm[c]);
    }
    __syncthreads();

    // G3: h2 = relu((fp-fm)@W1w[3:] + b1w + dxyz@W1w[0:3])
    mfma_tiles(&S.hbf[0][0], 136, WT1w, 128, 4, wv, lane, acc);
    float h2v[4][4];
#pragma unroll
    for (int i = 0; i < 4; ++i) {
      int col = (wv * 2 + (i >> 1)) * 16 + coli;
      float bb = b1w[col];
      float w0 = W1w[col], w1 = W1w[HID + col], w2 = W1w[2 * HID + col];
      int rowb = (i & 1) * 16 + rq;
#pragma unroll
      for (int r = 0; r < 4; ++r) {
        float4 dz = *(const float4*)S.dxyz[rowb + r];
        h2v[i][r] =
            fmaxf(acc[i][r] + bb + dz.x * w0 + dz.y * w1 + dz.z * w2, 0.f);
      }
    }
    __syncthreads();  // all G3 reads of hbf done
#pragma unroll
    for (int i = 0; i < 4; ++i) {
      int col = (wv * 2 + (i >> 1)) * 16 + coli;
      int rowb = (i & 1) * 16 + rq;
#pragma unroll
      for (int r = 0; r < 4; ++r) S.hbf[rowb + r][col] = f2bf(h2v[i][r]);
    }
    __syncthreads();

    // G4: alpha = sigmoid(h2 @ W2w + b2w); f_out[col] = sum_s alpha*fp
    mfma_tiles(&S.hbf[0][0], 136, WT2w, 128, 4, wv, lane, acc);
    {
      float psA = 0.f, psB = 0.f;
#pragma unroll
      for (int i = 0; i < 4; ++i) {
        int col = (wv * 2 + (i >> 1)) * 16 + coli;
        float bb = b2w[col];
        int rowb = (i & 1) * 16 + rq;
        float part = 0.f;
#pragma unroll
        for (int r = 0; r < 4; ++r) {
          float al = 1.0f / (1.0f + __expf(-(acc[i][r] + bb)));
          part += al * S.fp32[rowb + r][col];
        }
        if (i < 2) psA += part; else psB += part;
      }
      psA += __shfl_xor(psA, 16);
      psA += __shfl_xor(psA, 32);
      psB += __shfl_xor(psB, 16);
      psB += __shfl_xor(psB, 32);
      if (lane < 16) {
        fout[(size_t)g * HID + wv * 32 + lane] = psA;
        fout[(size_t)g * HID + wv * 32 + 16 + lane] = psB;
      }
    }
    __syncthreads();  // LDS fully consumed before next ticket
  }
}

// ---------------------------------------------------------------- fused
__global__ __launch_bounds__(256, 1) void sa_fused_kernel(
    const float* __restrict__ xyz, const float* __restrict__ feats,
    const unsigned short* __restrict__ wt, const float* __restrict__ b1f,
    const float* __restrict__ b2f, const float* __restrict__ W1w,
    const float* __restrict__ b1w, const float* __restrict__ b2w,
    float* __restrict__ newxyz, float* __restrict__ fout, int* ctrl) {
  __shared__ SMemU sm;
  int* progress = ctrl;    // [0..7]
  int* ticket = ctrl + 8;  // [8]
  if (blockIdx.x < NB) {
    run_fps(xyz, newxyz, progress, blockIdx.x, sm.p);
    __syncthreads();  // producer joins consumer pool for the tail
  }
  run_consumer(xyz, feats, wt, b1f, b2f, W1w, b1w, b2w, newxyz, fout,
               progress, ticket, sm.c);
}

extern "C" void kernel_launch(void* const* d_in, const int* in_sizes, int n_in,
                              void* d_out, int out_size, void* d_ws, size_t ws_size,
                              hipStream_t stream) {
  const float* xyz = (const float*)d_in[0];
  const float* feats = (const float*)d_in[1];
  const float* W1f = (const float*)d_in[2];
  const float* b1f = (const float*)d_in[3];
  const float* W2f = (const float*)d_in[4];
  const float* b2f = (const float*)d_in[5];
  const float* W1w = (const float*)d_in[6];
  const float* b1w = (const float*)d_in[7];
  const float* W2w = (const float*)d_in[8];
  const float* b2w = (const float*)d_in[9];

  float* newxyz = (float*)d_out;                          // (8,1024,3)
  float* fout = (float*)d_out + (size_t)NB * NPOINT * 3;  // (8,1024,128)
  int* ctrl = (int*)d_ws;                                 // progress[8]+ticket
  unsigned short* wt = (unsigned short*)((char*)d_ws + 256);  // 120KB bf16 W^T

  hipMemsetAsync(ctrl, 0, 64, stream);
  convert_w<<<240, 256, 0, stream>>>(W1f, W2f, W1w, W2w, wt);
  // 256 blocks x 256 thr, 84KB LDS -> 1 block/CU (producers solo, R10-proven
  // topology). Consumer GEMMs on MFMA (bf16): ~10x fewer instructions than
  // the f32 FMA stream that was latency-bound at ~8 q/us in R4-R11.
  sa_fused_kernel<<<256, 256, 0, stream>>>(xyz, feats, wt, b1f, b2f, W1w,
                                           b1w, b2w, newxyz, fout, ctrl);
}

// Round 13
// 798.321 us; speedup vs baseline: 2.3912x; 1.1044x over previous
//
#include <hip/hip_runtime.h>
#include <hip/hip_bf16.h>
#include <stdint.h>

#define NB 8
#define NPTS 4096
#define NPOINT 1024
#define NSAMPLE 32
#define FCH 64
#define HID 128
#define CAPW 160  // per-wave per-query candidate cap (expected ~15/segment)
#define NQ 4      // queries per consumer pass

typedef unsigned long long ull;
typedef __attribute__((ext_vector_type(8))) short short8;
typedef __attribute__((ext_vector_type(4))) float f32x4;

// d2 computed with EXACT numpy rounding/order: ((dx*dx + dy*dy) + dz*dz),
// no FMA contraction (FPS argmax + radius selection must match ref bitwise).
__device__ __forceinline__ float d2_exact(float ax, float ay, float az,
                                          float bx, float by, float bz) {
  float dx = ax - bx, dy = ay - by, dz = az - bz;
  return __fadd_rn(__fadd_rn(__fmul_rn(dx, dx), __fmul_rn(dy, dy)),
                   __fmul_rn(dz, dz));
}

__device__ __forceinline__ unsigned short f2bf(float x) {
  __hip_bfloat16 b = __float2bfloat16(x);
  unsigned short u;
  __builtin_memcpy(&u, &b, 2);
  return u;
}
__device__ __forceinline__ float bf2f(unsigned short u) {
  return __uint_as_float(((unsigned)u) << 16);  // bf16->f32 is exact
}

// DPP f32 max step (identity 0 valid: dists >= 0). VALU pipe.
#define DPPMAX(v, ctrl)                                                     \
  v = fmaxf(v, __int_as_float(__builtin_amdgcn_update_dpp(                  \
                 0, __float_as_int(v), ctrl, 0xf, 0xf, true)))

// ---------------- shared memory ---------------------------------------------
// R12 post-mortem: consumers still the limit at 9.3 q/us — 64K cyc/query of
// which only ~8K is MLP. Fix: NQ=4 queries/pass amortizes the fixed cost
// (xyz scan, poll/ticket, barriers, staging) 4x. fp stored bf16 to fit.
struct ProdS {
  float4 pts[NPTS];     // 64 KB
  float chunk[64 * 3];  // 64-centroid publish buffer
  float4 wkd4[2];       // per-wave max dist (parity dbuf)
  int4 wki4[2];         // per-wave argmax idx
};
struct ConsS {
  union {  // 34.8 KB: a1 (G1 A) / fpbf (G2 out, G4 in) / cand2 (knn)
    unsigned short a1[128][104];   // [dxyz,feats,0-pad..95] bf16
    unsigned short fpbf[128][136]; // f_prime bf16
    ull cand2[NQ][4 * CAPW];
  };
  union {  // 34.8 KB: hbf (h1 / fp-fm / h2) / candseg (knn)
    unsigned short hbf[128][136];
    ull candseg[4][NQ][CAPW];
  };
  float fm[NQ][HID];   // per-query mean (2 KB)
  float dxyz[128][4];  // f32 dxyz per sample (2 KB)
  int sidx[128];       // NQ x 32 sample indices
  int scnt[4][NQ];     // [wave][query] in-radius counts
  int tkS;
};
union SMemU {
  ProdS p;
  ConsS c;
  unsigned char pad_[86016];  // 84 KB > 80 KB -> 1 block/CU guaranteed
};

// ------------------------------------------------------- weight pre-convert
// d_ws layout (shorts, after 256B ctrl): WT1f[128][96] (k<67 else 0),
// WT2f[128][128], WT1w[128][128] (=W1w[3+k][n]), WT2w[128][128].
__global__ __launch_bounds__(256) void convert_w(const float* __restrict__ W1f,
                                                 const float* __restrict__ W2f,
                                                 const float* __restrict__ W1w,
                                                 const float* __restrict__ W2w,
                                                 unsigned short* __restrict__ wt) {
  int i = blockIdx.x * 256 + threadIdx.x;
  if (i >= 61440) return;
  float v;
  if (i < 12288) {
    int n = i / 96, k = i - n * 96;
    v = (k < 67) ? W1f[k * HID + n] : 0.f;
  } else if (i < 28672) {
    int j = i - 12288;
    int n = j >> 7, k = j & 127;
    v = W2f[k * HID + n];
  } else if (i < 45056) {
    int j = i - 28672;
    int n = j >> 7, k = j & 127;
    v = W1w[(k + 3) * HID + n];
  } else {
    int j = i - 45056;
    int n = j >> 7, k = j & 127;
    v = W2w[k * HID + n];
  }
  wt[i] = f2bf(v);
}

// ---------------------------------------------------------------- FPS
// R3/R4-proven chain (626us solo). Publishes centroids in 64-chunks.
__device__ void run_fps(const float* __restrict__ xyz,
                        float* __restrict__ newxyz, int* progress, int b,
                        ProdS& S) {
  const int t = threadIdx.x;
  const int wid = t >> 6;
  const float* src = xyz + (size_t)b * NPTS * 3;
  float* dstb = newxyz + (size_t)b * NPOINT * 3;
  for (int j = t; j < NPTS; j += 256) {
    const float* p = src + 3 * j;
    S.pts[j] = make_float4(p[0], p[1], p[2], 0.f);
  }
  __syncthreads();
  const int base = t * 16;
  float px[16], py[16], pz[16], dist[16];
  const float4 c0 = S.pts[0];
  float bv = -INFINITY;
  int br = 0;
#pragma unroll
  for (int r = 0; r < 16; ++r) {
    float4 p = S.pts[base + r];
    px[r] = p.x; py[r] = p.y; pz[r] = p.z;
    dist[r] = d2_exact(px[r], py[r], pz[r], c0.x, c0.y, c0.z);
    bool c = dist[r] > bv;  // strict > keeps lowest r (idx) on ties
    bv = c ? dist[r] : bv;
    br = c ? r : br;
  }
  if (t == 0) {
    S.chunk[0] = c0.x; S.chunk[1] = c0.y; S.chunk[2] = c0.z;
  }
  for (int it = 1; it < NPOINT; ++it) {
    float wm = bv;
    DPPMAX(wm, 0x111); DPPMAX(wm, 0x112); DPPMAX(wm, 0x114); DPPMAX(wm, 0x118);
    DPPMAX(wm, 0x142); DPPMAX(wm, 0x143);
    float gmaxw =
        __int_as_float(__builtin_amdgcn_readlane(__float_as_int(wm), 63));
    ull m = __ballot(bv == gmaxw);
    int lead = __ffsll((long long)m) - 1;  // lowest lane == lowest index
    int widx = __builtin_amdgcn_readlane(base + br, lead);
    const int par = it & 1;
    if ((t & 63) == 0) {
      ((float*)&S.wkd4[par])[wid] = gmaxw;
      ((int*)&S.wki4[par])[wid] = widx;
    }
    __syncthreads();  // parity double-buffer -> single barrier/iter
    if ((it & 63) == 0) {
      if (t < 192) {
        dstb[(it - 64) * 3 + t] = S.chunk[t];
        __threadfence();
      }
      __syncthreads();
      if (t == 0)
        __hip_atomic_store(&progress[b], it, __ATOMIC_RELEASE,
                           __HIP_MEMORY_SCOPE_AGENT);
    }
    float4 dd = S.wkd4[par];
    int4 ii = S.wki4[par];
    float d = dd.x; int fi = ii.x;
    bool c1 = (dd.y > d) || (dd.y == d && ii.y < fi);
    d = c1 ? dd.y : d; fi = c1 ? ii.y : fi;
    bool c2 = (dd.z > d) || (dd.z == d && ii.z < fi);
    d = c2 ? dd.z : d; fi = c2 ? ii.z : fi;
    bool c3 = (dd.w > d) || (dd.w == d && ii.w < fi);
    fi = c3 ? ii.w : fi;
    const float4 cp = S.pts[fi];
    if (t == 0) {
      int slot = (it & 63) * 3;
      S.chunk[slot + 0] = cp.x;
      S.chunk[slot + 1] = cp.y;
      S.chunk[slot + 2] = cp.z;
    }
    bv = -INFINITY;
    br = 0;
#pragma unroll
    for (int r = 0; r < 16; ++r) {
      float dnew = d2_exact(px[r], py[r], pz[r], cp.x, cp.y, cp.z);
      float nd = fminf(dist[r], dnew);
      dist[r] = nd;
      bool c = nd > bv;
      bv = c ? nd : bv;
      br = c ? r : br;
    }
  }
  __syncthreads();  // chunk holds centroids [960,1024)
  if (t < 192) {
    dstb[(NPOINT - 64) * 3 + t] = S.chunk[t];
    __threadfence();
  }
  __syncthreads();
  if (t == 0)
    __hip_atomic_store(&progress[b], NPOINT, __ATOMIC_RELEASE,
                       __HIP_MEMORY_SCOPE_AGENT);
}

// ----------------------------------------------------------- MFMA M=128 GEMM
// Wave wv owns n-tiles {2wv, 2wv+1} for all 8 m-tiles. HW-verified layouts:
// A/B-frag idx=lane&15, k=(lane>>4)*8+j [m120]; C/D col=lane&15,
// row=(lane>>4)*4+reg [m89/m91].
template <int KSTEPS>
__device__ __forceinline__ void mfma_gemm128(
    const unsigned short* __restrict__ A, int lda,
    const unsigned short* __restrict__ WT, int ldw, int wv, int lane,
    f32x4 acc[8][2]) {
  const int mi = lane & 15;
  const int qo = (lane >> 4) * 8;
  short8 bfr[2][KSTEPS];
#pragma unroll
  for (int ntl = 0; ntl < 2; ++ntl) {
    const int n = (wv * 2 + ntl) * 16 + mi;
#pragma unroll
    for (int ks = 0; ks < KSTEPS; ++ks)
      bfr[ntl][ks] = *(const short8*)(WT + (size_t)n * ldw + ks * 32 + qo);
  }
#pragma unroll
  for (int mt = 0; mt < 8; ++mt) {
    const int m = mt * 16 + mi;
    short8 af[KSTEPS];
#pragma unroll
    for (int ks = 0; ks < KSTEPS; ++ks)
      af[ks] = *(const short8*)(A + (size_t)m * lda + ks * 32 + qo);
#pragma unroll
    for (int ntl = 0; ntl < 2; ++ntl) {
      f32x4 a = acc[mt][ntl];
#pragma unroll
      for (int ks = 0; ks < KSTEPS; ++ks)
        a = __builtin_amdgcn_mfma_f32_16x16x32_bf16(af[ks], bfr[ntl][ks], a,
                                                    0, 0, 0);
      acc[mt][ntl] = a;
    }
  }
}

// ---------------------------------------------------------------- consumer
__device__ void run_consumer(const float* __restrict__ xyz,
                             const float* __restrict__ feats,
                             const unsigned short* __restrict__ wt,
                             const float* __restrict__ b1f,
                             const float* __restrict__ b2f,
                             const float* __restrict__ W1w,
                             const float* __restrict__ b1w,
                             const float* __restrict__ b2w,
                             const float* __restrict__ newxyz,
                             float* __restrict__ fout, int* progress,
                             int* ticket, ConsS& S) {
  const int t = threadIdx.x;
  const int wv = t >> 6;
  const int lane = t & 63;
  const float r2 = 0.0225f;  // np float32(RADIUS**2)
  const unsigned short* WT1f = wt;
  const unsigned short* WT2f = wt + 12288;
  const unsigned short* WT1w = wt + 28672;
  const unsigned short* WT2w = wt + 45056;

  while (true) {
    if (t == 0) S.tkS = atomicAdd(ticket, 1);
    __syncthreads();
    const int tk = S.tkS;
    if (tk >= NB * NPOINT / NQ) return;
    const int i4 = tk >> 3;      // quad index 0..255
    const int b = tk & 7;
    const int it0 = NQ * i4;     // queries it0..it0+3 of batch b
    const int g0 = b * NPOINT + it0;

    // wait until centroid it0+3 of batch b is published
    if (t == 0) {
      while (__hip_atomic_load(&progress[b], __ATOMIC_RELAXED,
                               __HIP_MEMORY_SCOPE_AGENT) <= it0 + NQ - 1)
        __builtin_amdgcn_s_sleep(32);
    }
    __syncthreads();
    {
      int pv = __hip_atomic_load(&progress[b], __ATOMIC_ACQUIRE,
                                 __HIP_MEMORY_SCOPE_AGENT);
      while (pv <= it0 + NQ - 1) {
        __builtin_amdgcn_s_sleep(8);
        pv = __hip_atomic_load(&progress[b], __ATOMIC_ACQUIRE,
                               __HIP_MEMORY_SCOPE_AGENT);
      }
    }
    const float* src = xyz + (size_t)b * NPTS * 3;
    float cxa[NQ], cya[NQ], cza[NQ];
#pragma unroll
    for (int q = 0; q < NQ; ++q) {
      cxa[q] = newxyz[(g0 + q) * 3 + 0];
      cya[q] = newxyz[(g0 + q) * 3 + 1];
      cza[q] = newxyz[(g0 + q) * 3 + 2];
    }

    // ---- knn: ONE scan of 4096 pts serves all 4 queries (4x load amort.)
    int cnt[NQ] = {0, 0, 0, 0};
    const int jb = wv * 1024;
    for (int j0 = jb; j0 < jb + 1024; j0 += 64) {
      const int p = j0 + lane;
      const float* pp = src + p * 3;
      float x = pp[0], y = pp[1], z = pp[2];
#pragma unroll
      for (int q = 0; q < NQ; ++q) {
        float d2 = d2_exact(x, y, z, cxa[q], cya[q], cza[q]);
        bool inr = (d2 <= r2);
        ull mask = __ballot(inr);
        if (inr) {
          int pos = cnt[q] + __popcll(mask & ((1ull << lane) - 1ull));
          if (pos < CAPW)
            S.candseg[wv][q][pos] =
                ((ull)__float_as_uint(d2) << 32) | (unsigned)p;
        }
        cnt[q] += __popcll(mask);
      }
    }
    if (lane == 0) {
#pragma unroll
      for (int q = 0; q < NQ; ++q)
        S.scnt[wv][q] = cnt[q] < CAPW ? cnt[q] : CAPW;
    }
    __syncthreads();
    // compaction + rank-select: wave wv handles query q=wv
    {
      const int q = wv;
      const int n0 = S.scnt[0][q], n1 = S.scnt[1][q], n2 = S.scnt[2][q],
                n3 = S.scnt[3][q];
      const int C = n0 + n1 + n2 + n3;
      int off = 0;
#pragma unroll
      for (int w = 0; w < 4; ++w) {
        int n = S.scnt[w][q];
        for (int i = lane; i < n; i += 64)
          S.cand2[q][off + i] = S.candseg[w][q][i];
        off += n;
      }
      // (single-wave data flow: candseg written pre-barrier, cand2 by this
      // wave only — no extra block barrier needed before rank)
      __builtin_amdgcn_wave_barrier();
      for (int tt = lane; tt < C; tt += 64) {
        ull key = S.cand2[q][tt];
        int rank = 0;
        for (int u = 0; u < C; ++u) rank += (S.cand2[q][u] < key) ? 1 : 0;
        if (rank < NSAMPLE) S.sidx[q * NSAMPLE + rank] = (int)(key & 0xffffffffu);
      }
      if (C < NSAMPLE) {  // boundary fill: lowest-index outside pts
        const float* pp = src + lane * 3;
        float d2 = d2_exact(pp[0], pp[1], pp[2], cxa[q], cya[q], cza[q]);
        bool outr = !(d2 <= r2);
        ull mask = __ballot(outr);
        if (outr) {
          int pos = __popcll(mask & ((1ull << lane) - 1ull));
          if (pos < NSAMPLE - C) S.sidx[q * NSAMPLE + C + pos] = lane;
        }
      }
    }
    __syncthreads();

    // ---- stage A for G1 (bf16) + dxyz f32 + zero-pad cols
    {  // zero a1 cols 68..103 (uint-aligned, 18 uints/row)
      int r = t >> 1, half = t & 1;
      unsigned int* rowp = (unsigned int*)&S.a1[r][68];
#pragma unroll
      for (int j = 0; j < 9; ++j) rowp[9 * half + j] = 0u;
    }
    if (t < 128) {
      const int q = t >> 5;
      const float* pp = src + (size_t)S.sidx[t] * 3;
      float dx = pp[0] - cxa[q], dy = pp[1] - cya[q], dz = pp[2] - cza[q];
      S.dxyz[t][0] = dx; S.dxyz[t][1] = dy; S.dxyz[t][2] = dz;
      S.dxyz[t][3] = 0.f;
      S.a1[t][0] = f2bf(dx); S.a1[t][1] = f2bf(dy); S.a1[t][2] = f2bf(dz);
      S.a1[t][67] = 0;
    }
    for (int e = t; e < 128 * FCH; e += 256) {
      int s = e >> 6;
      int c = e & 63;
      S.a1[s][3 + c] = f2bf(feats[((size_t)b * NPTS + S.sidx[s]) * FCH + c]);
    }
    __syncthreads();

    f32x4 acc[8][2];
    const int coli = lane & 15;
    const int rq = (lane >> 4) << 2;

    // G1: h1 = relu(f_in @ W1f + b1f), K=96 zero-padded -> hbf
#pragma unroll
    for (int mt = 0; mt < 8; ++mt)
#pragma unroll
      for (int ntl = 0; ntl < 2; ++ntl) acc[mt][ntl] = {0.f, 0.f, 0.f, 0.f};
    mfma_gemm128<3>(&S.a1[0][0], 104, WT1f, 96, wv, lane, acc);
#pragma unroll
    for (int ntl = 0; ntl < 2; ++ntl) {
      int col = (wv * 2 + ntl) * 16 + coli;
      float bb = b1f[col];
#pragma unroll
      for (int mt = 0; mt < 8; ++mt) {
        int rowb = mt * 16 + rq;
#pragma unroll
        for (int r = 0; r < 4; ++r)
          S.hbf[rowb + r][col] = f2bf(fmaxf(acc[mt][ntl][r] + bb, 0.f));
      }
    }
    __syncthreads();

    // G2: fp = relu(h1 @ W2f + b2f) -> fpbf
#pragma unroll
    for (int mt = 0; mt < 8; ++mt)
#pragma unroll
      for (int ntl = 0; ntl < 2; ++ntl) acc[mt][ntl] = {0.f, 0.f, 0.f, 0.f};
    mfma_gemm128<4>(&S.hbf[0][0], 136, WT2f, 128, wv, lane, acc);
#pragma unroll
    for (int ntl = 0; ntl < 2; ++ntl) {
      int col = (wv * 2 + ntl) * 16 + coli;
      float bb = b2f[col];
#pragma unroll
      for (int mt = 0; mt < 8; ++mt) {
        int rowb = mt * 16 + rq;
#pragma unroll
        for (int r = 0; r < 4; ++r)
          S.fpbf[rowb + r][col] = f2bf(fmaxf(acc[mt][ntl][r] + bb, 0.f));
      }
    }
    __syncthreads();

    // per-query mean over 32 samples (from bf16 fp)
    for (int e = t; e < NQ * HID; e += 256) {
      int q = e >> 7, c = e & 127;
      float s = 0.f;
#pragma unroll 8
      for (int i = 0; i < 32; ++i) s += bf2f(S.fpbf[q * 32 + i][c]);
      S.fm[q][c] = s * (1.0f / 32.0f);
    }
    __syncthreads();

    // G3 input: hbf <- bf16(fp - fm)  (h1 dead; uint-vectorized, 2 cols)
    for (int e = t; e < 128 * 64; e += 256) {
      int s = e >> 6, j = e & 63;
      int q = s >> 5;
      unsigned int pairv = *(unsigned int*)&S.fpbf[s][2 * j];
      float lo = bf2f((unsigned short)(pairv & 0xffff)) - S.fm[q][2 * j];
      float hi = bf2f((unsigned short)(pairv >> 16)) - S.fm[q][2 * j + 1];
      unsigned int outp = (unsigned int)f2bf(lo) | ((unsigned int)f2bf(hi) << 16);
      *(unsigned int*)&S.hbf[s][2 * j] = outp;
    }
    __syncthreads();

    // G3: h2 = relu((fp-fm)@W1w[3:] + b1w + dxyz@W1w[0:3])
#pragma unroll
    for (int mt = 0; mt < 8; ++mt)
#pragma unroll
      for (int ntl = 0; ntl < 2; ++ntl) acc[mt][ntl] = {0.f, 0.f, 0.f, 0.f};
    mfma_gemm128<4>(&S.hbf[0][0], 136, WT1w, 128, wv, lane, acc);
#pragma unroll
    for (int ntl = 0; ntl < 2; ++ntl) {
      int col = (wv * 2 + ntl) * 16 + coli;
      float bb = b1w[col];
      float w0 = W1w[col], w1 = W1w[HID + col], w2 = W1w[2 * HID + col];
#pragma unroll
      for (int mt = 0; mt < 8; ++mt) {
        int rowb = mt * 16 + rq;
#pragma unroll
        for (int r = 0; r < 4; ++r) {
          float4 dz = *(const float4*)S.dxyz[rowb + r];
          acc[mt][ntl][r] = fmaxf(
              acc[mt][ntl][r] + bb + dz.x * w0 + dz.y * w1 + dz.z * w2, 0.f);
        }
      }
    }
    __syncthreads();  // all G3 hbf reads done before overwrite
#pragma unroll
    for (int ntl = 0; ntl < 2; ++ntl) {
      int col = (wv * 2 + ntl) * 16 + coli;
#pragma unroll
      for (int mt = 0; mt < 8; ++mt) {
        int rowb = mt * 16 + rq;
#pragma unroll
        for (int r = 0; r < 4; ++r)
          S.hbf[rowb + r][col] = f2bf(acc[mt][ntl][r]);
      }
    }
    __syncthreads();

    // G4: alpha = sigmoid(h2 @ W2w + b2w); f_out = sum_s alpha * fp
#pragma unroll
    for (int mt = 0; mt < 8; ++mt)
#pragma unroll
      for (int ntl = 0; ntl < 2; ++ntl) acc[mt][ntl] = {0.f, 0.f, 0.f, 0.f};
    mfma_gemm128<4>(&S.hbf[0][0], 136, WT2w, 128, wv, lane, acc);
    {
      float ps[NQ][2];
#pragma unroll
      for (int q = 0; q < NQ; ++q) { ps[q][0] = 0.f; ps[q][1] = 0.f; }
#pragma unroll
      for (int ntl = 0; ntl < 2; ++ntl) {
        int col = (wv * 2 + ntl) * 16 + coli;
        float bb = b2w[col];
#pragma unroll
        for (int mt = 0; mt < 8; ++mt) {
          int rowb = mt * 16 + rq;
          float part = 0.f;
#pragma unroll
          for (int r = 0; r < 4; ++r) {
            float al = 1.0f / (1.0f + __expf(-(acc[mt][ntl][r] + bb)));
            part += al * bf2f(S.fpbf[rowb + r][col]);
          }
          ps[mt >> 1][ntl] += part;
        }
      }
#pragma unroll
      for (int q = 0; q < NQ; ++q)
#pragma unroll
        for (int ntl = 0; ntl < 2; ++ntl) {
          float v = ps[q][ntl];
          v += __shfl_xor(v, 16);
          v += __shfl_xor(v, 32);
          if (lane < 16)
            fout[(size_t)(g0 + q) * HID + (wv * 2 + ntl) * 16 + lane] = v;
        }
    }
    __syncthreads();  // LDS fully consumed before next ticket
  }
}

// ---------------------------------------------------------------- fused
__global__ __launch_bounds__(256, 1) void sa_fused_kernel(
    const float* __restrict__ xyz, const float* __restrict__ feats,
    const unsigned short* __restrict__ wt, const float* __restrict__ b1f,
    const float* __restrict__ b2f, const float* __restrict__ W1w,
    const float* __restrict__ b1w, const float* __restrict__ b2w,
    float* __restrict__ newxyz, float* __restrict__ fout, int* ctrl) {
  __shared__ SMemU sm;
  int* progress = ctrl;    // [0..7]
  int* ticket = ctrl + 8;  // [8]
  if (blockIdx.x < NB) {
    run_fps(xyz, newxyz, progress, blockIdx.x, sm.p);
    __syncthreads();  // producer joins consumer pool for the tail
  }
  run_consumer(xyz, feats, wt, b1f, b2f, W1w, b1w, b2w, newxyz, fout,
               progress, ticket, sm.c);
}

extern "C" void kernel_launch(void* const* d_in, const int* in_sizes, int n_in,
                              void* d_out, int out_size, void* d_ws, size_t ws_size,
                              hipStream_t stream) {
  const float* xyz = (const float*)d_in[0];
  const float* feats = (const float*)d_in[1];
  const float* W1f = (const float*)d_in[2];
  const float* b1f = (const float*)d_in[3];
  const float* W2f = (const float*)d_in[4];
  const float* b2f = (const float*)d_in[5];
  const float* W1w = (const float*)d_in[6];
  const float* b1w = (const float*)d_in[7];
  const float* W2w = (const float*)d_in[8];
  const float* b2w = (const float*)d_in[9];

  float* newxyz = (float*)d_out;                          // (8,1024,3)
  float* fout = (float*)d_out + (size_t)NB * NPOINT * 3;  // (8,1024,128)
  int* ctrl = (int*)d_ws;                                 // progress[8]+ticket
  unsigned short* wt = (unsigned short*)((char*)d_ws + 256);  // 120KB bf16 W^T

  hipMemsetAsync(ctrl, 0, 64, stream);
  convert_w<<<240, 256, 0, stream>>>(W1f, W2f, W1w, W2w, wt);
  // 256 blocks x 256 thr, 84KB LDS -> 1 block/CU (producers solo, R10
  // topology). Consumer: NQ=4 queries/pass — one xyz scan + one sync
  // skeleton per 4 queries; MLP = M=128 bf16 MFMA GEMMs.
  sa_fused_kernel<<<256, 256, 0, stream>>>(xyz, feats, wt, b1f, b2f, W1w,
                                           b1w, b2w, newxyz, fout, ctrl);
}

// Round 14
// 769.840 us; speedup vs baseline: 2.4797x; 1.0370x over previous
//
#include <hip/hip_runtime.h>
#include <hip/hip_bf16.h>
#include <stdint.h>

#define NB 8
#define NPTS 4096
#define NPOINT 1024
#define NSAMPLE 32
#define FCH 64
#define HID 128
#define CAPW 160  // per-wave per-query candidate cap (expected ~15/segment)
#define NQ 4      // queries per consumer pass

typedef unsigned long long ull;
typedef __attribute__((ext_vector_type(8))) short short8;
typedef __attribute__((ext_vector_type(4))) float f32x4;

// d2 computed with EXACT numpy rounding/order: ((dx*dx + dy*dy) + dz*dz),
// no FMA contraction (FPS argmax + radius selection must match ref bitwise).
__device__ __forceinline__ float d2_exact(float ax, float ay, float az,
                                          float bx, float by, float bz) {
  float dx = ax - bx, dy = ay - by, dz = az - bz;
  return __fadd_rn(__fadd_rn(__fmul_rn(dx, dx), __fmul_rn(dy, dy)),
                   __fmul_rn(dz, dz));
}

__device__ __forceinline__ unsigned short f2bf(float x) {
  __hip_bfloat16 b = __float2bfloat16(x);
  unsigned short u;
  __builtin_memcpy(&u, &b, 2);
  return u;
}
__device__ __forceinline__ float bf2f(unsigned short u) {
  return __uint_as_float(((unsigned)u) << 16);  // bf16->f32 is exact
}

// DPP f32 max step (identity 0 valid: dists >= 0). VALU pipe.
#define DPPMAX(v, ctrl)                                                     \
  v = fmaxf(v, __int_as_float(__builtin_amdgcn_update_dpp(                  \
                 0, __float_as_int(v), ctrl, 0xf, 0xf, true)))

// ---------------- shared memory ---------------------------------------------
struct ProdS {
  float4 pts[NPTS];     // 64 KB
  float chunk[64 * 3];  // 64-centroid publish buffer
  float4 wkd4[2];       // per-wave max dist (parity dbuf)
  int4 wki4[2];         // per-wave argmax idx
};
struct ConsS {
  union {  // a1 (G1 A) / fpbf (G2 out, G4 in) / cand2 (knn)
    unsigned short a1[128][104];    // [dxyz,feats,0-pad..95] bf16
    unsigned short fpbf[128][136];  // f_prime bf16
    ull cand2[NQ][4 * CAPW];
  };
  union {  // hbf (h1 / fp-fm / h2) / candseg (knn)
    unsigned short hbf[128][136];
    ull candseg[4][NQ][CAPW];
  };
  float fm[NQ][HID];   // per-query mean
  float dxyz[128][4];  // f32 dxyz per sample
  int sidx[128];       // NQ x 32 sample indices
  int scnt[4][NQ];     // [wave][query] in-radius counts
  int tkS;
};
union SMemU {
  ProdS p;
  ConsS c;
  unsigned char pad_[86016];  // 84 KB > 80 KB -> 1 block/CU guaranteed
};

// ---------------------------------------------------------------- FPS
// R13 chain + restructured argmax: hot loop is pure min-update (9 instr/pt),
// wave max via fmaxf tree (v_max3, 3-deep), local index found AFTER the DPP
// reduce (overlaps its latency). Exactness: all comparisons on exact f32;
// ties -> lowest index at thread (scan-down), lane (ballot lead), and wave
// (CMB idx tiebreak) levels == np.argmax first-occurrence.
__device__ void run_fps(const float* __restrict__ xyz,
                        float* __restrict__ newxyz, int* progress, int b,
                        ProdS& S) {
  const int t = threadIdx.x;
  const int wid = t >> 6;
  const float* src = xyz + (size_t)b * NPTS * 3;
  float* dstb = newxyz + (size_t)b * NPOINT * 3;
  for (int j = t; j < NPTS; j += 256) {
    const float* p = src + 3 * j;
    S.pts[j] = make_float4(p[0], p[1], p[2], 0.f);
  }
  __syncthreads();
  const int base = t * 16;
  float px[16], py[16], pz[16], dist[16];
  const float4 c0 = S.pts[0];
#pragma unroll
  for (int r = 0; r < 16; ++r) {
    float4 p = S.pts[base + r];
    px[r] = p.x; py[r] = p.y; pz[r] = p.z;
    dist[r] = d2_exact(px[r], py[r], pz[r], c0.x, c0.y, c0.z);
  }
  if (t == 0) {
    S.chunk[0] = c0.x; S.chunk[1] = c0.y; S.chunk[2] = c0.z;
  }
  for (int it = 1; it < NPOINT; ++it) {
    // wave-local max via balanced tree (-> v_max3_f32)
    float m0 = fmaxf(fmaxf(dist[0], dist[1]), fmaxf(dist[2], dist[3]));
    float m1 = fmaxf(fmaxf(dist[4], dist[5]), fmaxf(dist[6], dist[7]));
    float m2 = fmaxf(fmaxf(dist[8], dist[9]), fmaxf(dist[10], dist[11]));
    float m3 = fmaxf(fmaxf(dist[12], dist[13]), fmaxf(dist[14], dist[15]));
    float wmx = fmaxf(fmaxf(m0, m1), fmaxf(m2, m3));
    float wm = wmx;
    DPPMAX(wm, 0x111); DPPMAX(wm, 0x112); DPPMAX(wm, 0x114); DPPMAX(wm, 0x118);
    DPPMAX(wm, 0x142); DPPMAX(wm, 0x143);
    // local first-match index (overlaps DPP/readlane latency)
    int br = 15;
#pragma unroll
    for (int r = 14; r >= 0; --r) br = (dist[r] == wmx) ? r : br;
    float gmaxw =
        __int_as_float(__builtin_amdgcn_readlane(__float_as_int(wm), 63));
    ull m = __ballot(wmx == gmaxw);
    int lead = __ffsll((long long)m) - 1;  // lowest lane == lowest index
    int widx = __builtin_amdgcn_readlane(base + br, lead);
    const int par = it & 1;
    if ((t & 63) == 0) {
      ((float*)&S.wkd4[par])[wid] = gmaxw;
      ((int*)&S.wki4[par])[wid] = widx;
    }
    __syncthreads();  // parity double-buffer -> single barrier/iter
    if ((it & 63) == 0) {
      if (t < 192) {
        dstb[(it - 64) * 3 + t] = S.chunk[t];
        __threadfence();
      }
      __syncthreads();
      if (t == 0)
        __hip_atomic_store(&progress[b], it, __ATOMIC_RELEASE,
                           __HIP_MEMORY_SCOPE_AGENT);
    }
    float4 dd = S.wkd4[par];
    int4 ii = S.wki4[par];
    float d = dd.x; int fi = ii.x;
    bool c1 = (dd.y > d) || (dd.y == d && ii.y < fi);
    d = c1 ? dd.y : d; fi = c1 ? ii.y : fi;
    bool c2 = (dd.z > d) || (dd.z == d && ii.z < fi);
    d = c2 ? dd.z : d; fi = c2 ? ii.z : fi;
    bool c3 = (dd.w > d) || (dd.w == d && ii.w < fi);
    fi = c3 ? ii.w : fi;
    const float4 cp = S.pts[fi];
    if (t == 0) {
      int slot = (it & 63) * 3;
      S.chunk[slot + 0] = cp.x;
      S.chunk[slot + 1] = cp.y;
      S.chunk[slot + 2] = cp.z;
    }
#pragma unroll
    for (int r = 0; r < 16; ++r) {
      float dnew = d2_exact(px[r], py[r], pz[r], cp.x, cp.y, cp.z);
      dist[r] = fminf(dist[r], dnew);
    }
  }
  __syncthreads();  // chunk holds centroids [960,1024)
  if (t < 192) {
    dstb[(NPOINT - 64) * 3 + t] = S.chunk[t];
    __threadfence();
  }
  __syncthreads();
  if (t == 0)
    __hip_atomic_store(&progress[b], NPOINT, __ATOMIC_RELEASE,
                       __HIP_MEMORY_SCOPE_AGENT);
}

// ----------------------------------------------------------- MFMA M=128 GEMM
// Wave wv owns n-tiles {2wv, 2wv+1} for all 8 m-tiles. HW-verified layouts:
// A/B-frag idx=lane&15, k=(lane>>4)*8+j [m120]; C/D col=lane&15,
// row=(lane>>4)*4+reg [m89/m91].
template <int KSTEPS>
__device__ __forceinline__ void mfma_gemm128(
    const unsigned short* __restrict__ A, int lda,
    const unsigned short* __restrict__ WT, int ldw, int wv, int lane,
    f32x4 acc[8][2]) {
  const int mi = lane & 15;
  const int qo = (lane >> 4) * 8;
  short8 bfr[2][KSTEPS];
#pragma unroll
  for (int ntl = 0; ntl < 2; ++ntl) {
    const int n = (wv * 2 + ntl) * 16 + mi;
#pragma unroll
    for (int ks = 0; ks < KSTEPS; ++ks)
      bfr[ntl][ks] = *(const short8*)(WT + (size_t)n * ldw + ks * 32 + qo);
  }
#pragma unroll
  for (int mt = 0; mt < 8; ++mt) {
    const int m = mt * 16 + mi;
    short8 af[KSTEPS];
#pragma unroll
    for (int ks = 0; ks < KSTEPS; ++ks)
      af[ks] = *(const short8*)(A + (size_t)m * lda + ks * 32 + qo);
#pragma unroll
    for (int ntl = 0; ntl < 2; ++ntl) {
      f32x4 a = acc[mt][ntl];
#pragma unroll
      for (int ks = 0; ks < KSTEPS; ++ks)
        a = __builtin_amdgcn_mfma_f32_16x16x32_bf16(af[ks], bfr[ntl][ks], a,
                                                    0, 0, 0);
      acc[mt][ntl] = a;
    }
  }
}

// ---------------------------------------------------------------- consumer
__device__ void run_consumer(const float* __restrict__ xyz,
                             const float* __restrict__ feats,
                             const unsigned short* __restrict__ wt,
                             const float* __restrict__ b1f,
                             const float* __restrict__ b2f,
                             const float* __restrict__ W1w,
                             const float* __restrict__ b1w,
                             const float* __restrict__ b2w,
                             const float* __restrict__ newxyz,
                             float* __restrict__ fout, int* progress,
                             int* ticket, ConsS& S) {
  const int t = threadIdx.x;
  const int wv = t >> 6;
  const int lane = t & 63;
  const float r2 = 0.0225f;  // np float32(RADIUS**2)
  const unsigned short* WT1f = wt;
  const unsigned short* WT2f = wt + 12288;
  const unsigned short* WT1w = wt + 28672;
  const unsigned short* WT2w = wt + 45056;

  while (true) {
    if (t == 0) S.tkS = atomicAdd(ticket, 1);
    __syncthreads();
    const int tk = S.tkS;
    if (tk >= NB * NPOINT / NQ) return;
    const int i4 = tk >> 3;   // quad index 0..255
    const int b = tk & 7;
    const int it0 = NQ * i4;  // queries it0..it0+3 of batch b
    const int g0 = b * NPOINT + it0;

    // wait until centroid it0+3 of batch b is published
    if (t == 0) {
      while (__hip_atomic_load(&progress[b], __ATOMIC_RELAXED,
                               __HIP_MEMORY_SCOPE_AGENT) <= it0 + NQ - 1)
        __builtin_amdgcn_s_sleep(32);
    }
    __syncthreads();
    {
      int pv = __hip_atomic_load(&progress[b], __ATOMIC_ACQUIRE,
                                 __HIP_MEMORY_SCOPE_AGENT);
      while (pv <= it0 + NQ - 1) {
        __builtin_amdgcn_s_sleep(8);
        pv = __hip_atomic_load(&progress[b], __ATOMIC_ACQUIRE,
                               __HIP_MEMORY_SCOPE_AGENT);
      }
    }
    const float* src = xyz + (size_t)b * NPTS * 3;
    float cxa[NQ], cya[NQ], cza[NQ];
#pragma unroll
    for (int q = 0; q < NQ; ++q) {
      cxa[q] = newxyz[(g0 + q) * 3 + 0];
      cya[q] = newxyz[(g0 + q) * 3 + 1];
      cza[q] = newxyz[(g0 + q) * 3 + 2];
    }

    // ---- knn: ONE scan of 4096 pts serves all 4 queries
    int cnt[NQ] = {0, 0, 0, 0};
    const int jb = wv * 1024;
    for (int j0 = jb; j0 < jb + 1024; j0 += 64) {
      const int p = j0 + lane;
      const float* pp = src + p * 3;
      float x = pp[0], y = pp[1], z = pp[2];
#pragma unroll
      for (int q = 0; q < NQ; ++q) {
        float d2 = d2_exact(x, y, z, cxa[q], cya[q], cza[q]);
        bool inr = (d2 <= r2);
        ull mask = __ballot(inr);
        if (inr) {
          int pos = cnt[q] + __popcll(mask & ((1ull << lane) - 1ull));
          if (pos < CAPW)
            S.candseg[wv][q][pos] =
                ((ull)__float_as_uint(d2) << 32) | (unsigned)p;
        }
        cnt[q] += __popcll(mask);
      }
    }
    if (lane == 0) {
#pragma unroll
      for (int q = 0; q < NQ; ++q)
        S.scnt[wv][q] = cnt[q] < CAPW ? cnt[q] : CAPW;
    }
    __syncthreads();
    // compaction + rank-select: wave wv handles query q=wv
    {
      const int q = wv;
      const int n0 = S.scnt[0][q], n1 = S.scnt[1][q], n2 = S.scnt[2][q],
                n3 = S.scnt[3][q];
      const int C = n0 + n1 + n2 + n3;
      int off = 0;
#pragma unroll
      for (int w = 0; w < 4; ++w) {
        int n = S.scnt[w][q];
        for (int i = lane; i < n; i += 64)
          S.cand2[q][off + i] = S.candseg[w][q][i];
        off += n;
      }
      __builtin_amdgcn_wave_barrier();
      for (int tt = lane; tt < C; tt += 64) {
        ull key = S.cand2[q][tt];
        int rank = 0;
        for (int u = 0; u < C; ++u) rank += (S.cand2[q][u] < key) ? 1 : 0;
        if (rank < NSAMPLE)
          S.sidx[q * NSAMPLE + rank] = (int)(key & 0xffffffffu);
      }
      if (C < NSAMPLE) {  // boundary fill: lowest-index outside pts
        const float* pp = src + lane * 3;
        float d2 = d2_exact(pp[0], pp[1], pp[2], cxa[q], cya[q], cza[q]);
        bool outr = !(d2 <= r2);
        ull mask = __ballot(outr);
        if (outr) {
          int pos = __popcll(mask & ((1ull << lane) - 1ull));
          if (pos < NSAMPLE - C) S.sidx[q * NSAMPLE + C + pos] = lane;
        }
      }
    }
    __syncthreads();

    // ---- stage A for G1 (bf16) + dxyz f32 + zero-pad cols
    {  // zero a1 cols 68..103 (uint-aligned, 18 uints/row)
      int r = t >> 1, half = t & 1;
      unsigned int* rowp = (unsigned int*)&S.a1[r][68];
#pragma unroll
      for (int j = 0; j < 9; ++j) rowp[9 * half + j] = 0u;
    }
    if (t < 128) {
      const int q = t >> 5;
      const float* pp = src + (size_t)S.sidx[t] * 3;
      float dx = pp[0] - cxa[q], dy = pp[1] - cya[q], dz = pp[2] - cza[q];
      S.dxyz[t][0] = dx; S.dxyz[t][1] = dy; S.dxyz[t][2] = dz;
      S.dxyz[t][3] = 0.f;
      S.a1[t][0] = f2bf(dx); S.a1[t][1] = f2bf(dy); S.a1[t][2] = f2bf(dz);
      S.a1[t][67] = 0;
    }
    for (int e = t; e < 128 * FCH; e += 256) {
      int s = e >> 6;
      int c = e & 63;
      S.a1[s][3 + c] = f2bf(feats[((size_t)b * NPTS + S.sidx[s]) * FCH + c]);
    }
    __syncthreads();

    f32x4 acc[8][2];
    const int coli = lane & 15;
    const int rq = (lane >> 4) << 2;

    // G1: h1 = relu(f_in @ W1f + b1f), K=96 zero-padded -> hbf
#pragma unroll
    for (int mt = 0; mt < 8; ++mt)
#pragma unroll
      for (int ntl = 0; ntl < 2; ++ntl) acc[mt][ntl] = {0.f, 0.f, 0.f, 0.f};
    mfma_gemm128<3>(&S.a1[0][0], 104, WT1f, 96, wv, lane, acc);
#pragma unroll
    for (int ntl = 0; ntl < 2; ++ntl) {
      int col = (wv * 2 + ntl) * 16 + coli;
      float bb = b1f[col];
#pragma unroll
      for (int mt = 0; mt < 8; ++mt) {
        int rowb = mt * 16 + rq;
#pragma unroll
        for (int r = 0; r < 4; ++r)
          S.hbf[rowb + r][col] = f2bf(fmaxf(acc[mt][ntl][r] + bb, 0.f));
      }
    }
    __syncthreads();

    // G2: fp = relu(h1 @ W2f + b2f) -> fpbf
#pragma unroll
    for (int mt = 0; mt < 8; ++mt)
#pragma unroll
      for (int ntl = 0; ntl < 2; ++ntl) acc[mt][ntl] = {0.f, 0.f, 0.f, 0.f};
    mfma_gemm128<4>(&S.hbf[0][0], 136, WT2f, 128, wv, lane, acc);
#pragma unroll
    for (int ntl = 0; ntl < 2; ++ntl) {
      int col = (wv * 2 + ntl) * 16 + coli;
      float bb = b2f[col];
#pragma unroll
      for (int mt = 0; mt < 8; ++mt) {
        int rowb = mt * 16 + rq;
#pragma unroll
        for (int r = 0; r < 4; ++r)
          S.fpbf[rowb + r][col] = f2bf(fmaxf(acc[mt][ntl][r] + bb, 0.f));
      }
    }
    __syncthreads();

    // per-query mean over 32 samples (from bf16 fp)
    for (int e = t; e < NQ * HID; e += 256) {
      int q = e >> 7, c = e & 127;
      float s = 0.f;
#pragma unroll 8
      for (int i = 0; i < 32; ++i) s += bf2f(S.fpbf[q * 32 + i][c]);
      S.fm[q][c] = s * (1.0f / 32.0f);
    }
    __syncthreads();

    // G3 input: hbf <- bf16(fp - fm)  (h1 dead; uint-vectorized)
    for (int e = t; e < 128 * 64; e += 256) {
      int s = e >> 6, j = e & 63;
      int q = s >> 5;
      unsigned int pairv = *(unsigned int*)&S.fpbf[s][2 * j];
      float lo = bf2f((unsigned short)(pairv & 0xffff)) - S.fm[q][2 * j];
      float hi = bf2f((unsigned short)(pairv >> 16)) - S.fm[q][2 * j + 1];
      unsigned int outp =
          (unsigned int)f2bf(lo) | ((unsigned int)f2bf(hi) << 16);
      *(unsigned int*)&S.hbf[s][2 * j] = outp;
    }
    __syncthreads();

    // G3: h2 = relu((fp-fm)@W1w[3:] + b1w + dxyz@W1w[0:3])
#pragma unroll
    for (int mt = 0; mt < 8; ++mt)
#pragma unroll
      for (int ntl = 0; ntl < 2; ++ntl) acc[mt][ntl] = {0.f, 0.f, 0.f, 0.f};
    mfma_gemm128<4>(&S.hbf[0][0], 136, WT1w, 128, wv, lane, acc);
#pragma unroll
    for (int ntl = 0; ntl < 2; ++ntl) {
      int col = (wv * 2 + ntl) * 16 + coli;
      float bb = b1w[col];
      float w0 = W1w[col], w1 = W1w[HID + col], w2 = W1w[2 * HID + col];
#pragma unroll
      for (int mt = 0; mt < 8; ++mt) {
        int rowb = mt * 16 + rq;
#pragma unroll
        for (int r = 0; r < 4; ++r) {
          float4 dz = *(const float4*)S.dxyz[rowb + r];
          acc[mt][ntl][r] = fmaxf(
              acc[mt][ntl][r] + bb + dz.x * w0 + dz.y * w1 + dz.z * w2, 0.f);
        }
      }
    }
    __syncthreads();  // all G3 hbf reads done before overwrite
#pragma unroll
    for (int ntl = 0; ntl < 2; ++ntl) {
      int col = (wv * 2 + ntl) * 16 + coli;
#pragma unroll
      for (int mt = 0; mt < 8; ++mt) {
        int rowb = mt * 16 + rq;
#pragma unroll
        for (int r = 0; r < 4; ++r)
          S.hbf[rowb + r][col] = f2bf(acc[mt][ntl][r]);
      }
    }
    __syncthreads();

    // G4: alpha = sigmoid(h2 @ W2w + b2w); f_out = sum_s alpha * fp
#pragma unroll
    for (int mt = 0; mt < 8; ++mt)
#pragma unroll
      for (int ntl = 0; ntl < 2; ++ntl) acc[mt][ntl] = {0.f, 0.f, 0.f, 0.f};
    mfma_gemm128<4>(&S.hbf[0][0], 136, WT2w, 128, wv, lane, acc);
    {
      float ps[NQ][2];
#pragma unroll
      for (int q = 0; q < NQ; ++q) { ps[q][0] = 0.f; ps[q][1] = 0.f; }
#pragma unroll
      for (int ntl = 0; ntl < 2; ++ntl) {
        int col = (wv * 2 + ntl) * 16 + coli;
        float bb = b2w[col];
#pragma unroll
        for (int mt = 0; mt < 8; ++mt) {
          int rowb = mt * 16 + rq;
          float part = 0.f;
#pragma unroll
          for (int r = 0; r < 4; ++r) {
            float al = 1.0f / (1.0f + __expf(-(acc[mt][ntl][r] + bb)));
            part += al * bf2f(S.fpbf[rowb + r][col]);
          }
          ps[mt >> 1][ntl] += part;
        }
      }
#pragma unroll
      for (int q = 0; q < NQ; ++q)
#pragma unroll
        for (int ntl = 0; ntl < 2; ++ntl) {
          float v = ps[q][ntl];
          v += __shfl_xor(v, 16);
          v += __shfl_xor(v, 32);
          if (lane < 16)
            fout[(size_t)(g0 + q) * HID + (wv * 2 + ntl) * 16 + lane] = v;
        }
    }
    __syncthreads();  // LDS fully consumed before next ticket
  }
}

// ---------------------------------------------------------------- fused
__global__ __launch_bounds__(256, 1) void sa_fused_kernel(
    const float* __restrict__ xyz, const float* __restrict__ feats,
    const float* __restrict__ W1f, const float* __restrict__ b1f,
    const float* __restrict__ W2f, const float* __restrict__ b2f,
    const float* __restrict__ W1w, const float* __restrict__ b1w,
    const float* __restrict__ W2w, const float* __restrict__ b2w,
    unsigned short* __restrict__ wt, float* __restrict__ newxyz,
    float* __restrict__ fout, int* ctrl) {
  __shared__ SMemU sm;
  int* progress = ctrl;    // [0..7]
  int* ticket = ctrl + 8;  // [8]
  if (blockIdx.x < NB) {
    // producers skip conversion: FPS (the critical path) starts immediately.
    // When they later join the consumer pool, their XCD's L2 holds wt lines
    // written by the ~31 consumer blocks sharing that XCD.
    run_fps(xyz, newxyz, progress, blockIdx.x, sm.p);
    __syncthreads();
  } else {
    // Each consumer block converts the FULL 120KB bf16 W^T itself
    // (identical redundant writes are benign; removes the separate
    // convert_w dispatch AND any cross-block ordering requirement).
    const int t = threadIdx.x;
    for (int i = t; i < 61440; i += 256) {
      float v;
      if (i < 12288) {
        int n = i / 96, k = i - n * 96;
        v = (k < 67) ? W1f[k * HID + n] : 0.f;
      } else if (i < 28672) {
        int j = i - 12288;
        int n = j >> 7, k = j & 127;
        v = W2f[k * HID + n];
      } else if (i < 45056) {
        int j = i - 28672;
        int n = j >> 7, k = j & 127;
        v = W1w[(k + 3) * HID + n];
      } else {
        int j = i - 45056;
        int n = j >> 7, k = j & 127;
        v = W2w[k * HID + n];
      }
      wt[i] = f2bf(v);
    }
    __threadfence_block();
    __syncthreads();  // own conversion visible block-wide before use
  }
  run_consumer(xyz, feats, wt, b1f, b2f, W1w, b1w, b2w, newxyz, fout,
               progress, ticket, sm.c);
}

extern "C" void kernel_launch(void* const* d_in, const int* in_sizes, int n_in,
                              void* d_out, int out_size, void* d_ws, size_t ws_size,
                              hipStream_t stream) {
  const float* xyz = (const float*)d_in[0];
  const float* feats = (const float*)d_in[1];
  const float* W1f = (const float*)d_in[2];
  const float* b1f = (const float*)d_in[3];
  const float* W2f = (const float*)d_in[4];
  const float* b2f = (const float*)d_in[5];
  const float* W1w = (const float*)d_in[6];
  const float* b1w = (const float*)d_in[7];
  const float* W2w = (const float*)d_in[8];
  const float* b2w = (const float*)d_in[9];

  float* newxyz = (float*)d_out;                          // (8,1024,3)
  float* fout = (float*)d_out + (size_t)NB * NPOINT * 3;  // (8,1024,128)
  int* ctrl = (int*)d_ws;                                 // progress[8]+ticket
  unsigned short* wt = (unsigned short*)((char*)d_ws + 256);  // 120KB bf16 W^T

  hipMemsetAsync(ctrl, 0, 64, stream);
  // 256 blocks x 256 thr, 84KB LDS -> 1 block/CU (producers solo, R10
  // topology). Producer chain: restructured argmax (pure min-update hot
  // loop + max3 tree + deferred index). Weight conversion folded into
  // consumer-block startup (one less dispatch).
  sa_fused_kernel<<<256, 256, 0, stream>>>(xyz, feats, W1f, b1f, W2f, b2f,
                                           W1w, b1w, W2w, b2w, wt, newxyz,
                                           fout, ctrl);
}